// Round 12
// baseline (4457.976 us; speedup 1.0000x reference)
//
#include <hip/hip_runtime.h>
#include <stdint.h>

// DCRNN forward, MI355X — R12: EXACT R5 stage protocol (best measured: 2305us,
// FETCH 106MB), re-geometried to 2 blocks/batch x 1024 threads (128 blocks).
//  - Why: R8-R11 protocol perturbations were all neutral-to-negative; R5's
//    pipeline is the proven one. Geometry change halves state read
//    amplification (2 blocks read full state, not 4), narrows the barrier to
//    2 arrivals, and doubles waves/SIMD (2->4) for latency hiding.
//  - prep: A = {S0, 2S0^2-I, S1, 2S1^2-I} bf16, packed weights, zero hidden,
//    reset barriers. main: 128 blocks x 1024 thr = 64 batches x 2 row-halves;
//    102400 B LDS -> 1 block/CU -> all co-resident; per-batch 2-block barrier
//    (relaxed agent atomics; blocks i, i+8 share XCD i&7).
//  - State exchange: 8B agent-scope atomic stores/loads (R5 path).
//  - h/u in MFMA-fragment registers across all 48 cells.

typedef short short8 __attribute__((ext_vector_type(8)));
typedef float f32x4 __attribute__((ext_vector_type(4)));
typedef unsigned short ushort4v __attribute__((ext_vector_type(4)));
typedef unsigned long long u64;
typedef u64 u64x2 __attribute__((ext_vector_type(2)));

#define DEVI __device__ __forceinline__

DEVI unsigned short f2bf(float x) {
  unsigned int u = __builtin_bit_cast(unsigned int, x);
  u += 0x7FFFu + ((u >> 16) & 1u);  // RNE
  return (unsigned short)(u >> 16);
}
DEVI u64 ald(const u64* p) { return __hip_atomic_load(p, __ATOMIC_RELAXED, __HIP_MEMORY_SCOPE_AGENT); }
DEVI void ast(u64* p, u64 v) { __hip_atomic_store(p, v, __ATOMIC_RELAXED, __HIP_MEMORY_SCOPE_AGENT); }
DEVI float aldf(const float* p) { return __hip_atomic_load(p, __ATOMIC_RELAXED, __HIP_MEMORY_SCOPE_AGENT); }
DEVI void astf(float* p, float v) { __hip_atomic_store(p, v, __ATOMIC_RELAXED, __HIP_MEMORY_SCOPE_AGENT); }

struct KP {
  const float* enc_in;
  const float* sup0; const float* sup1;
  const float* Wsrc[8];
  const float* bias[8];
  const float* prW; const float* prB;
  float* out;
  unsigned short* A;        // [4][256][256] bf16
  unsigned short* Wp[8];    // packed [O][5*FP] bf16
  unsigned short* H0[2];    // [64 b][64 f][256 n] bf16 rows, ping-pong
  unsigned short* H1[2];
  unsigned short* RH0;      // r*h rows
  unsigned short* RH1;
  float* XD;                // [64][256] decoder feedback
  unsigned* ctr;            // 64 per-batch counters, 256B apart
};

// ---------------- prep kernel (512 blocks x 256) ----------------
__global__ void prep(KP p) {
  const int i = blockIdx.x, tid = threadIdx.x;
  {  // A matrices
    const int s = i & 1, r = i >> 1;
    const float* S = s ? p.sup1 : p.sup0;
    float acc = 0.f;
    for (int k = 0; k < 256; ++k) acc = fmaf(S[r * 256 + k], S[k * 256 + tid], acc);
    p.A[(2 * s + 0) * 65536 + r * 256 + tid] = f2bf(S[r * 256 + tid]);
    p.A[(2 * s + 1) * 65536 + r * 256 + tid] = f2bf(2.f * acc - (r == tid ? 1.f : 0.f));
  }
  {  // packed weights: Wp[o][m*FP+f] = W[f,m,o], f zero-padded to FP
    const int gtid = i * 256 + tid;
    const int Fs[8]  = {66, 66, 128, 128, 65, 65, 128, 128};
    const int Os[8]  = {128, 64, 128, 64, 128, 64, 128, 64};
    const int FPs[8] = {96, 96, 128, 128, 96, 96, 128, 128};
    for (int w = 0; w < 8; ++w) {
      const int FPw = FPs[w], KPw = 5 * FPw, tot = Os[w] * KPw;
      for (int e = gtid; e < tot; e += 512 * 256) {
        const int o = e / KPw, k2 = e - o * KPw, m = k2 / FPw, f = k2 - m * FPw;
        p.Wp[w][e] = f2bf((f < Fs[w]) ? p.Wsrc[w][(f * 5 + m) * Os[w] + o] : 0.f);
      }
    }
  }
  {  // zero initial hidden via agent-scope stores
    const int gtid = i * 256 + tid;
    u64* z0 = (u64*)p.H0[0];
    u64* z1 = (u64*)p.H1[0];
    ast(z0 + 2 * gtid, 0); ast(z0 + 2 * gtid + 1, 0);
    ast(z1 + 2 * gtid, 0); ast(z1 + 2 * gtid + 1, 0);
  }
  if (i == 0 && tid < 64)
    __hip_atomic_store(p.ctr + tid * 64, 0u, __ATOMIC_RELAXED, __HIP_MEMORY_SCOPE_AGENT);
}

// ---------------- fused diffusion-conv stage (R5 protocol, 128 rows/block) ----------------
// MODE 0: gates (O=128, sigmoid; writes RH rows, u regs)
// MODE 1: cand  (O=64, tanh; GRU update of hreg; writes H rows)
// MODE 2: MODE1 + final projection (writes out slice and XD)
template<int IND, int FP, int MODE>
DEVI void dc_stage(int b, int n0, int tid,
                   const float* xf32,             // IND<=2 x input (IND==1 via agent ld)
                   const unsigned short* xbf,     // IND==64 bf16 rows [64][256]
                   const unsigned short* hrows,   // bf16 rows [64][256] (h or r*h)
                   const unsigned short* Amats,
                   const unsigned short* Wp, const float* bias,
                   f32x4 (&hreg)[2], f32x4 (&ureg)[2],
                   unsigned short* grows,         // output rows (RH or Hnew)
                   const float* projW, const float* projB,
                   float* outp, float* xdout,
                   unsigned short* xsT, unsigned short* Hbuf)
{
  constexpr int F = IND + 64;
  constexpr int O = (MODE == 0) ? 128 : 64;
  constexpr int KPW = 5 * FP;
  constexpr int XS = 264;            // xsT row stride (bf16 elems)
  constexpr int HS = 136;            // Hbuf row stride
  constexpr int NFT = FP / 16;
  constexpr int NOT_ = O / 16;
  constexpr int FT_W = (NFT + 3) / 4;
  constexpr int OT_W = (NOT_ + 3) / 4;

  const int wv8 = tid >> 6, ln = tid & 63;   // 16 waves
  const int l15 = ln & 15, l4 = ln >> 4;
  const int wr = wv8 & 3, wc = wv8 >> 2;     // 4 row-groups x 4 col-groups
  const int r0 = wr * 32;

  // ---- build xsT [f][n]: state rows via agent-scope u64 loads (R5 path) ----
  // 64 rows x 256 cols bf16 = 2048 16B chunks; chunk g: row=g>>5, c=g&31.
  {
    u64 la[2], lb[2];
    const u64* src = (const u64*)hrows;
#pragma unroll
    for (int it = 0; it < 2; ++it) {
      const int g = tid + it * 1024;
      la[it] = ald(src + 2 * g); lb[it] = ald(src + 2 * g + 1);
    }
#pragma unroll
    for (int it = 0; it < 2; ++it) {
      const int g = tid + it * 1024, row = g >> 5, c = g & 31;
      u64x2 v; v[0] = la[it]; v[1] = lb[it];
      *reinterpret_cast<u64x2*>(&xsT[(IND + row) * XS + c * 8]) = v;
    }
  }
  if (IND == 64) {
    u64 la[2], lb[2];
    const u64* src = (const u64*)xbf;
#pragma unroll
    for (int it = 0; it < 2; ++it) {
      const int g = tid + it * 1024;
      la[it] = ald(src + 2 * g); lb[it] = ald(src + 2 * g + 1);
    }
#pragma unroll
    for (int it = 0; it < 2; ++it) {
      const int g = tid + it * 1024, row = g >> 5, c = g & 31;
      u64x2 v; v[0] = la[it]; v[1] = lb[it];
      *reinterpret_cast<u64x2*>(&xsT[row * XS + c * 8]) = v;
    }
  } else if (IND == 2) {
    if (tid < 512) {
      const float v = xf32[tid];             // read-only input, cached
      xsT[(tid & 1) * XS + (tid >> 1)] = f2bf(v);
    }
  } else {  // IND == 1 (decoder feedback)
    if (tid < 256) xsT[tid] = xf32 ? f2bf(aldf(xf32 + tid)) : (unsigned short)0;
  }
  if (F < FP) {
    for (int e = tid; e < (FP - F) * 256; e += 1024)
      xsT[(F + (e >> 8)) * XS + (e & 255)] = 0;
  }
  __syncthreads();
  // ---- Hbuf = transpose of xsT columns [n0,n0+128): [nl][f] ----
#pragma unroll
  for (int it = 0; it < FP / 8; ++it) {
    const int e = tid + it * 1024, f = e >> 7, nl = e & 127;
    Hbuf[nl * HS + f] = xsT[f * XS + n0 + nl];
  }
  __syncthreads();

  f32x4 pacc[2][OT_W];
#pragma unroll
  for (int rt = 0; rt < 2; ++rt)
#pragma unroll
    for (int oi = 0; oi < OT_W; ++oi) pacc[rt][oi] = 0.f;

  auto proj_step = [&](int m) {
#pragma unroll
    for (int k0 = 0; k0 < FP; k0 += 32) {
      short8 af[2];
#pragma unroll
      for (int rt = 0; rt < 2; ++rt)
        af[rt] = *reinterpret_cast<const short8*>(&Hbuf[(r0 + rt * 16 + l15) * HS + k0 + l4 * 8]);
#pragma unroll
      for (int oi = 0; oi < OT_W; ++oi) {
        const int ot = wc + 4 * oi;
        if (ot < NOT_) {
          short8 bf = *reinterpret_cast<const short8*>(&Wp[(ot * 16 + l15) * KPW + m * FP + k0 + l4 * 8]);
#pragma unroll
          for (int rt = 0; rt < 2; ++rt)
            pacc[rt][oi] = __builtin_amdgcn_mfma_f32_16x16x32_bf16(af[rt], bf, pacc[rt][oi], 0, 0, 0);
        }
      }
    }
  };

  proj_step(0);  // identity slice

  for (int mi = 0; mi < 4; ++mi) {
    const unsigned short* Am = Amats + mi * 65536;
    f32x4 hacc[2][FT_W];
#pragma unroll
    for (int rt = 0; rt < 2; ++rt)
#pragma unroll
      for (int fi = 0; fi < FT_W; ++fi) hacc[rt][fi] = 0.f;

#pragma unroll
    for (int k0 = 0; k0 < 256; k0 += 32) {
      short8 af[2];
#pragma unroll
      for (int rt = 0; rt < 2; ++rt)
        af[rt] = *reinterpret_cast<const short8*>(&Am[(n0 + r0 + rt * 16 + l15) * 256 + k0 + l4 * 8]);
#pragma unroll
      for (int fi = 0; fi < FT_W; ++fi) {
        const int ft = wc + 4 * fi;
        if (ft < NFT) {
          short8 bf = *reinterpret_cast<const short8*>(&xsT[(ft * 16 + l15) * XS + k0 + l4 * 8]);
#pragma unroll
          for (int rt = 0; rt < 2; ++rt)
            hacc[rt][fi] = __builtin_amdgcn_mfma_f32_16x16x32_bf16(af[rt], bf, hacc[rt][fi], 0, 0, 0);
        }
      }
    }
    __syncthreads();   // previous proj_step readers of Hbuf done
#pragma unroll
    for (int fi = 0; fi < FT_W; ++fi) {
      const int ft = wc + 4 * fi;
      if (ft < NFT) {
#pragma unroll
        for (int rt = 0; rt < 2; ++rt)
#pragma unroll
          for (int j = 0; j < 4; ++j)
            Hbuf[(r0 + rt * 16 + l4 * 4 + j) * HS + ft * 16 + l15] = f2bf(hacc[rt][fi][j]);
      }
    }
    __syncthreads();
    proj_step(mi + 1);
  }

  // ---- epilogue ----
  if (MODE == 0) {
    const float br = bias[wc * 16 + l15];
    const float bu = bias[64 + wc * 16 + l15];
#pragma unroll
    for (int rt = 0; rt < 2; ++rt) {
      f32x4 uu;
      ushort4v pk;
#pragma unroll
      for (int jj = 0; jj < 4; ++jj) {
        const float r = 1.f / (1.f + __expf(-(pacc[rt][0][jj] + br)));
        uu[jj] = 1.f / (1.f + __expf(-(pacc[rt][1][jj] + bu)));
        pk[jj] = f2bf(r * hreg[rt][jj]);
      }
      ureg[rt] = uu;
      ast((u64*)(grows + (wc * 16 + l15) * 256 + n0 + r0 + rt * 16 + l4 * 4),
          __builtin_bit_cast(u64, pk));
    }
  } else {
    float* hrow = reinterpret_cast<float*>(Hbuf);   // [128][68] fp32 overlay
    if (MODE == 2) __syncthreads();                 // proj(4) readers done
    const float bc = bias[wc * 16 + l15];
#pragma unroll
    for (int rt = 0; rt < 2; ++rt) {
      f32x4 hn;
      ushort4v pk;
#pragma unroll
      for (int jj = 0; jj < 4; ++jj) {
        const float ex = __expf(2.f * (pacc[rt][0][jj] + bc));
        const float c = 1.f - 2.f / (ex + 1.f);     // tanh
        hn[jj] = ureg[rt][jj] * hreg[rt][jj] + (1.f - ureg[rt][jj]) * c;
        pk[jj] = f2bf(hn[jj]);
      }
      hreg[rt] = hn;
      ast((u64*)(grows + (wc * 16 + l15) * 256 + n0 + r0 + rt * 16 + l4 * 4),
          __builtin_bit_cast(u64, pk));
      if (MODE == 2) {
#pragma unroll
        for (int jj = 0; jj < 4; ++jj)
          hrow[(r0 + rt * 16 + l4 * 4 + jj) * 68 + wc * 16 + l15] = hn[jj];
      }
    }
    if (MODE == 2) {
      __syncthreads();
      if (tid < 128) {
        float acc = projB[0];
        const float* hr = hrow + tid * 68;
#pragma unroll
        for (int hid = 0; hid < 64; ++hid) acc = fmaf(hr[hid], projW[hid], acc);
        outp[b * 3072 + n0 + tid] = acc;            // host-read output
        astf(xdout + b * 256 + n0 + tid, acc);      // cross-block feedback
      }
    }
  }
}

// ---------------- persistent main kernel (128 blocks x 1024) ----------------
__launch_bounds__(1024, 4)
__global__ void dcrnn_main(KP p) {
  __shared__ __align__(16) unsigned short xsT[128 * 264];   // 67584 B
  __shared__ __align__(16) unsigned short Hbuf[128 * 136];  // 34816 B -> 102400, 1 blk/CU
  const int tid = threadIdx.x;
  const int i = (int)blockIdx.x;
  const int q = (i >> 3) & 1;
  const int b = (i & 7) + 8 * (i >> 4);   // batch's 2 blocks (i, i+8) share XCD i&7
  const int n0 = q * 128;

  unsigned* ctr = p.ctr + b * 64;
  unsigned st = 0;
  auto BAR = [&]() {
    ++st;
    asm volatile("s_waitcnt vmcnt(0)" ::: "memory");  // state stores visible
    __syncthreads();
    if (tid == 0) {
      __hip_atomic_fetch_add(ctr, 1u, __ATOMIC_RELAXED, __HIP_MEMORY_SCOPE_AGENT);
      const unsigned target = st * 2u;
      while (__hip_atomic_load(ctr, __ATOMIC_RELAXED, __HIP_MEMORY_SCOPE_AGENT) < target)
        __builtin_amdgcn_s_sleep(2);
    }
    __syncthreads();
  };

  f32x4 h0[2], h1[2], u[2];
#pragma unroll
  for (int rt = 0; rt < 2; ++rt) { h0[rt] = 0.f; h1[rt] = 0.f; u[rt] = 0.f; }
  int c0 = 0, c1 = 0;

  // ---- encoder ----
  for (int t = 0; t < 12; ++t) {
    const float* x0 = p.enc_in + (b * 12 + t) * 512;
    dc_stage<2, 96, 0>(b, n0, tid, x0, nullptr, p.H0[c0] + b * 16384, p.A, p.Wp[0], p.bias[0],
                       h0, u, p.RH0 + b * 16384, nullptr, nullptr, nullptr, nullptr, xsT, Hbuf);
    BAR();
    dc_stage<2, 96, 1>(b, n0, tid, x0, nullptr, p.RH0 + b * 16384, p.A, p.Wp[1], p.bias[1],
                       h0, u, p.H0[c0 ^ 1] + b * 16384, nullptr, nullptr, nullptr, nullptr, xsT, Hbuf);
    BAR(); c0 ^= 1;
    dc_stage<64, 128, 0>(b, n0, tid, nullptr, p.H0[c0] + b * 16384, p.H1[c1] + b * 16384, p.A, p.Wp[2], p.bias[2],
                         h1, u, p.RH1 + b * 16384, nullptr, nullptr, nullptr, nullptr, xsT, Hbuf);
    BAR();
    dc_stage<64, 128, 1>(b, n0, tid, nullptr, p.H0[c0] + b * 16384, p.RH1 + b * 16384, p.A, p.Wp[3], p.bias[3],
                         h1, u, p.H1[c1 ^ 1] + b * 16384, nullptr, nullptr, nullptr, nullptr, xsT, Hbuf);
    BAR(); c1 ^= 1;
  }

  // ---- decoder ----
  for (int t = 0; t < 12; ++t) {
    const float* xd = t ? (p.XD + b * 256) : nullptr;
    dc_stage<1, 96, 0>(b, n0, tid, xd, nullptr, p.H0[c0] + b * 16384, p.A, p.Wp[4], p.bias[4],
                       h0, u, p.RH0 + b * 16384, nullptr, nullptr, nullptr, nullptr, xsT, Hbuf);
    BAR();
    dc_stage<1, 96, 1>(b, n0, tid, xd, nullptr, p.RH0 + b * 16384, p.A, p.Wp[5], p.bias[5],
                       h0, u, p.H0[c0 ^ 1] + b * 16384, nullptr, nullptr, nullptr, nullptr, xsT, Hbuf);
    BAR(); c0 ^= 1;
    dc_stage<64, 128, 0>(b, n0, tid, nullptr, p.H0[c0] + b * 16384, p.H1[c1] + b * 16384, p.A, p.Wp[6], p.bias[6],
                         h1, u, p.RH1 + b * 16384, nullptr, nullptr, nullptr, nullptr, xsT, Hbuf);
    BAR();
    dc_stage<64, 128, 2>(b, n0, tid, nullptr, p.H0[c0] + b * 16384, p.RH1 + b * 16384, p.A, p.Wp[7], p.bias[7],
                         h1, u, p.H1[c1 ^ 1] + b * 16384, p.prW, p.prB, p.out + t * 256, p.XD, xsT, Hbuf);
    if (t != 11) BAR();
    c1 ^= 1;
  }
}

// ---------------- host ----------------
extern "C" void kernel_launch(void* const* d_in, const int* in_sizes, int n_in,
                              void* d_out, int out_size, void* d_ws, size_t ws_size,
                              hipStream_t stream)
{
  (void)in_sizes; (void)n_in; (void)out_size; (void)ws_size;
  KP p;
  p.enc_in = (const float*)d_in[0];
  p.sup0 = (const float*)d_in[2];
  p.sup1 = (const float*)d_in[3];
  p.Wsrc[0] = (const float*)d_in[4];  p.bias[0] = (const float*)d_in[5];
  p.Wsrc[1] = (const float*)d_in[6];  p.bias[1] = (const float*)d_in[7];
  p.Wsrc[2] = (const float*)d_in[8];  p.bias[2] = (const float*)d_in[9];
  p.Wsrc[3] = (const float*)d_in[10]; p.bias[3] = (const float*)d_in[11];
  p.Wsrc[4] = (const float*)d_in[12]; p.bias[4] = (const float*)d_in[13];
  p.Wsrc[5] = (const float*)d_in[14]; p.bias[5] = (const float*)d_in[15];
  p.Wsrc[6] = (const float*)d_in[16]; p.bias[6] = (const float*)d_in[17];
  p.Wsrc[7] = (const float*)d_in[18]; p.bias[7] = (const float*)d_in[19];
  p.prW = (const float*)d_in[20];
  p.prB = (const float*)d_in[21];
  p.out = (float*)d_out;

  char* ws = (char*)d_ws;
  size_t off = 0;
  auto carve = [&](size_t bytes) -> char* {
    char* qp = ws + off;
    off += (bytes + 255) & ~(size_t)255;
    return qp;
  };
  p.A = (unsigned short*)carve(4 * 65536 * 2);
  p.Wp[0] = (unsigned short*)carve(128 * 480 * 2);
  p.Wp[1] = (unsigned short*)carve(64 * 480 * 2);
  p.Wp[2] = (unsigned short*)carve(128 * 640 * 2);
  p.Wp[3] = (unsigned short*)carve(64 * 640 * 2);
  p.Wp[4] = (unsigned short*)carve(128 * 480 * 2);
  p.Wp[5] = (unsigned short*)carve(64 * 480 * 2);
  p.Wp[6] = (unsigned short*)carve(128 * 640 * 2);
  p.Wp[7] = (unsigned short*)carve(64 * 640 * 2);
  p.H0[0] = (unsigned short*)carve(64 * 64 * 256 * 2);
  p.H0[1] = (unsigned short*)carve(64 * 64 * 256 * 2);
  p.H1[0] = (unsigned short*)carve(64 * 64 * 256 * 2);
  p.H1[1] = (unsigned short*)carve(64 * 64 * 256 * 2);
  p.RH0 = (unsigned short*)carve(64 * 64 * 256 * 2);
  p.RH1 = (unsigned short*)carve(64 * 64 * 256 * 2);
  p.XD = (float*)carve(64 * 256 * 4);
  p.ctr = (unsigned*)carve(64 * 256);

  prep<<<dim3(512), dim3(256), 0, stream>>>(p);
  dcrnn_main<<<dim3(128), dim3(1024), 0, stream>>>(p);
}

// Round 13
// 2278.380 us; speedup vs baseline: 1.9566x; 1.9566x over previous
//
#include <hip/hip_runtime.h>
#include <stdint.h>

// DCRNN forward, MI355X — R13 = R5 byte-exact protocol/geometry (best: 2305us)
// + cand stages skip re-staging the x-part (retained in xsT from the gates
// stage; xsT is untouched between them) + pad zeroing moved to a one-time
// prologue (xsT only ever holds finite bf16; Wp zero pad cols annihilate).
//  - main: 256 blocks x 512 threads = 64 batches x 4 row-quadrants; 84992 B LDS
//    forces 1 block/CU -> all 256 blocks co-resident. Per-batch 4-block barrier
//    (relaxed agent atomics; batch's blocks share blockIdx%8 -> same XCD).
//  - State exchange: 8B agent-scope atomic stores/loads (R5-proven path).
//  - h/u state in MFMA-fragment registers across all 48 cells.
//  - LDS-roofline note: 64 rows/block at 2x2 register blocking ~253 GB/s/CU,
//    just under the ~307 GB/s/CU LDS ceiling — why R12's 128-row blocks lost.

typedef short short8 __attribute__((ext_vector_type(8)));
typedef float f32x4 __attribute__((ext_vector_type(4)));
typedef unsigned short ushort4v __attribute__((ext_vector_type(4)));
typedef unsigned long long u64;
typedef u64 u64x2 __attribute__((ext_vector_type(2)));

#define DEVI __device__ __forceinline__

DEVI unsigned short f2bf(float x) {
  unsigned int u = __builtin_bit_cast(unsigned int, x);
  u += 0x7FFFu + ((u >> 16) & 1u);  // RNE
  return (unsigned short)(u >> 16);
}
DEVI u64 ald(const u64* p) { return __hip_atomic_load(p, __ATOMIC_RELAXED, __HIP_MEMORY_SCOPE_AGENT); }
DEVI void ast(u64* p, u64 v) { __hip_atomic_store(p, v, __ATOMIC_RELAXED, __HIP_MEMORY_SCOPE_AGENT); }
DEVI float aldf(const float* p) { return __hip_atomic_load(p, __ATOMIC_RELAXED, __HIP_MEMORY_SCOPE_AGENT); }
DEVI void astf(float* p, float v) { __hip_atomic_store(p, v, __ATOMIC_RELAXED, __HIP_MEMORY_SCOPE_AGENT); }

struct KP {
  const float* enc_in;
  const float* sup0; const float* sup1;
  const float* Wsrc[8];
  const float* bias[8];
  const float* prW; const float* prB;
  float* out;
  unsigned short* A;        // [4][256][256] bf16
  unsigned short* Wp[8];    // packed [O][5*FP] bf16
  unsigned short* H0[2];    // [64 b][64 f][256 n] bf16 rows, ping-pong
  unsigned short* H1[2];
  unsigned short* RH0;      // r*h rows
  unsigned short* RH1;
  float* XD;                // [64][256] decoder feedback
  unsigned* ctr;            // 64 per-batch counters, 256B apart
};

// ---------------- prep kernel (512 blocks x 256) ----------------
__global__ void prep(KP p) {
  const int i = blockIdx.x, tid = threadIdx.x;
  {  // A matrices
    const int s = i & 1, r = i >> 1;
    const float* S = s ? p.sup1 : p.sup0;
    float acc = 0.f;
    for (int k = 0; k < 256; ++k) acc = fmaf(S[r * 256 + k], S[k * 256 + tid], acc);
    p.A[(2 * s + 0) * 65536 + r * 256 + tid] = f2bf(S[r * 256 + tid]);
    p.A[(2 * s + 1) * 65536 + r * 256 + tid] = f2bf(2.f * acc - (r == tid ? 1.f : 0.f));
  }
  {  // packed weights: Wp[o][m*FP+f] = W[f,m,o], f zero-padded to FP
    const int gtid = i * 256 + tid;
    const int Fs[8]  = {66, 66, 128, 128, 65, 65, 128, 128};
    const int Os[8]  = {128, 64, 128, 64, 128, 64, 128, 64};
    const int FPs[8] = {96, 96, 128, 128, 96, 96, 128, 128};
    for (int w = 0; w < 8; ++w) {
      const int FPw = FPs[w], KPw = 5 * FPw, tot = Os[w] * KPw;
      for (int e = gtid; e < tot; e += 512 * 256) {
        const int o = e / KPw, k2 = e - o * KPw, m = k2 / FPw, f = k2 - m * FPw;
        p.Wp[w][e] = f2bf((f < Fs[w]) ? p.Wsrc[w][(f * 5 + m) * Os[w] + o] : 0.f);
      }
    }
  }
  {  // zero initial hidden via agent-scope stores
    const int gtid = i * 256 + tid;
    u64* z0 = (u64*)p.H0[0];
    u64* z1 = (u64*)p.H1[0];
    ast(z0 + 2 * gtid, 0); ast(z0 + 2 * gtid + 1, 0);
    ast(z1 + 2 * gtid, 0); ast(z1 + 2 * gtid + 1, 0);
  }
  if (i == 0 && tid < 64)
    __hip_atomic_store(p.ctr + tid * 64, 0u, __ATOMIC_RELAXED, __HIP_MEMORY_SCOPE_AGENT);
}

// ---------------- fused diffusion-conv stage (R5 protocol) ----------------
// MODE 0: gates (O=128, sigmoid; writes RH rows, u regs)
// MODE 1: cand  (O=64, tanh; GRU update of hreg; writes H rows)
// MODE 2: MODE1 + final projection (writes out slice and XD)
// XSTAGE: stage the x-part into xsT (gates). Cand stages skip it — xsT is
// untouched between a cell's gates and cand stages, so the x-part persists.
template<int IND, int FP, int MODE, bool XSTAGE>
DEVI void dc_stage(int b, int n0, int tid,
                   const float* xf32,             // IND<=2 x input (IND==1 via agent ld)
                   const unsigned short* xbf,     // IND==64 bf16 rows [64][256]
                   const unsigned short* hrows,   // bf16 rows [64][256] (h or r*h)
                   const unsigned short* Amats,
                   const unsigned short* Wp, const float* bias,
                   f32x4 (&hreg)[2], f32x4 (&ureg)[2],
                   unsigned short* grows,         // output rows (RH or Hnew)
                   const float* projW, const float* projB,
                   float* outp, float* xdout,
                   unsigned short* xsT, unsigned short* Hbuf)
{
  constexpr int O = (MODE == 0) ? 128 : 64;
  constexpr int KPW = 5 * FP;
  constexpr int XS = 264;            // xsT row stride (bf16 elems)
  constexpr int HS = 136;            // Hbuf row stride
  constexpr int NFT = FP / 16;
  constexpr int NOT_ = O / 16;
  constexpr int FT_W = (NFT + 3) / 4;
  constexpr int OT_W = (NOT_ + 3) / 4;

  const int wv8 = tid >> 6, ln = tid & 63;
  const int l15 = ln & 15, l4 = ln >> 4;
  const int wr = wv8 & 1, wc = wv8 >> 1;   // row-half / tile-column quarter
  const int r0 = wr * 32;

  // ---- build xsT [f][n]: h-part always; x-part only when XSTAGE ----
  {
    u64 la[4], lb[4];
    const u64* src = (const u64*)hrows;
#pragma unroll
    for (int it = 0; it < 4; ++it) {
      const int g = tid + it * 512;
      la[it] = ald(src + 2 * g); lb[it] = ald(src + 2 * g + 1);
    }
#pragma unroll
    for (int it = 0; it < 4; ++it) {
      const int g = tid + it * 512, row = g >> 5, c = g & 31;
      u64x2 v; v[0] = la[it]; v[1] = lb[it];
      *reinterpret_cast<u64x2*>(&xsT[(IND + row) * XS + c * 8]) = v;
    }
  }
  if (XSTAGE) {
    if (IND == 64) {
      u64 la[4], lb[4];
      const u64* src = (const u64*)xbf;
#pragma unroll
      for (int it = 0; it < 4; ++it) {
        const int g = tid + it * 512;
        la[it] = ald(src + 2 * g); lb[it] = ald(src + 2 * g + 1);
      }
#pragma unroll
      for (int it = 0; it < 4; ++it) {
        const int g = tid + it * 512, row = g >> 5, c = g & 31;
        u64x2 v; v[0] = la[it]; v[1] = lb[it];
        *reinterpret_cast<u64x2*>(&xsT[row * XS + c * 8]) = v;
      }
    } else if (IND == 2) {
      const float v = xf32[tid];               // read-only input, cached
      xsT[(tid & 1) * XS + (tid >> 1)] = f2bf(v);
    } else {  // IND == 1 (decoder feedback)
      if (tid < 256) xsT[tid] = xf32 ? f2bf(aldf(xf32 + tid)) : (unsigned short)0;
    }
  }
  // pads [IND+64, FP): zeroed once in prologue; between stages xsT only ever
  // holds finite bf16, and Wp's zero pad columns annihilate stale values.
  __syncthreads();
  // ---- Hbuf = transpose of xsT columns [n0,n0+64): [nl][f] ----
#pragma unroll
  for (int it = 0; it < FP / 8; ++it) {
    const int e = tid + it * 512, f = e >> 6, nl = e & 63;
    Hbuf[nl * HS + f] = xsT[f * XS + n0 + nl];
  }
  __syncthreads();

  f32x4 pacc[2][OT_W];
#pragma unroll
  for (int rt = 0; rt < 2; ++rt)
#pragma unroll
    for (int oi = 0; oi < OT_W; ++oi) pacc[rt][oi] = 0.f;

  auto proj_step = [&](int m) {
#pragma unroll
    for (int k0 = 0; k0 < FP; k0 += 32) {
      short8 af[2];
#pragma unroll
      for (int rt = 0; rt < 2; ++rt)
        af[rt] = *reinterpret_cast<const short8*>(&Hbuf[(r0 + rt * 16 + l15) * HS + k0 + l4 * 8]);
#pragma unroll
      for (int oi = 0; oi < OT_W; ++oi) {
        const int ot = wc + 4 * oi;
        if (ot < NOT_) {
          short8 bf = *reinterpret_cast<const short8*>(&Wp[(ot * 16 + l15) * KPW + m * FP + k0 + l4 * 8]);
#pragma unroll
          for (int rt = 0; rt < 2; ++rt)
            pacc[rt][oi] = __builtin_amdgcn_mfma_f32_16x16x32_bf16(af[rt], bf, pacc[rt][oi], 0, 0, 0);
        }
      }
    }
  };

  proj_step(0);  // identity slice

  for (int mi = 0; mi < 4; ++mi) {
    const unsigned short* Am = Amats + mi * 65536;
    f32x4 hacc[2][FT_W];
#pragma unroll
    for (int rt = 0; rt < 2; ++rt)
#pragma unroll
      for (int fi = 0; fi < FT_W; ++fi) hacc[rt][fi] = 0.f;

#pragma unroll
    for (int k0 = 0; k0 < 256; k0 += 32) {
      short8 af[2];
#pragma unroll
      for (int rt = 0; rt < 2; ++rt)
        af[rt] = *reinterpret_cast<const short8*>(&Am[(n0 + r0 + rt * 16 + l15) * 256 + k0 + l4 * 8]);
#pragma unroll
      for (int fi = 0; fi < FT_W; ++fi) {
        const int ft = wc + 4 * fi;
        if (ft < NFT) {
          short8 bf = *reinterpret_cast<const short8*>(&xsT[(ft * 16 + l15) * XS + k0 + l4 * 8]);
#pragma unroll
          for (int rt = 0; rt < 2; ++rt)
            hacc[rt][fi] = __builtin_amdgcn_mfma_f32_16x16x32_bf16(af[rt], bf, hacc[rt][fi], 0, 0, 0);
        }
      }
    }
    __syncthreads();   // previous proj_step readers of Hbuf done
#pragma unroll
    for (int fi = 0; fi < FT_W; ++fi) {
      const int ft = wc + 4 * fi;
      if (ft < NFT) {
#pragma unroll
        for (int rt = 0; rt < 2; ++rt)
#pragma unroll
          for (int j = 0; j < 4; ++j)
            Hbuf[(r0 + rt * 16 + l4 * 4 + j) * HS + ft * 16 + l15] = f2bf(hacc[rt][fi][j]);
      }
    }
    __syncthreads();
    proj_step(mi + 1);
  }

  // ---- epilogue ----
  if (MODE == 0) {
    const float br = bias[wc * 16 + l15];
    const float bu = bias[64 + wc * 16 + l15];
#pragma unroll
    for (int rt = 0; rt < 2; ++rt) {
      f32x4 uu;
      ushort4v pk;
#pragma unroll
      for (int jj = 0; jj < 4; ++jj) {
        const float r = 1.f / (1.f + __expf(-(pacc[rt][0][jj] + br)));
        uu[jj] = 1.f / (1.f + __expf(-(pacc[rt][1][jj] + bu)));
        pk[jj] = f2bf(r * hreg[rt][jj]);
      }
      ureg[rt] = uu;
      ast((u64*)(grows + (wc * 16 + l15) * 256 + n0 + r0 + rt * 16 + l4 * 4),
          __builtin_bit_cast(u64, pk));
    }
  } else {
    float* hrow = reinterpret_cast<float*>(Hbuf);   // [64][68] fp32 overlay
    if (MODE == 2) __syncthreads();                 // proj(4) readers done
    const float bc = bias[wc * 16 + l15];
#pragma unroll
    for (int rt = 0; rt < 2; ++rt) {
      f32x4 hn;
      ushort4v pk;
#pragma unroll
      for (int jj = 0; jj < 4; ++jj) {
        const float ex = __expf(2.f * (pacc[rt][0][jj] + bc));
        const float c = 1.f - 2.f / (ex + 1.f);     // tanh
        hn[jj] = ureg[rt][jj] * hreg[rt][jj] + (1.f - ureg[rt][jj]) * c;
        pk[jj] = f2bf(hn[jj]);
      }
      hreg[rt] = hn;
      ast((u64*)(grows + (wc * 16 + l15) * 256 + n0 + r0 + rt * 16 + l4 * 4),
          __builtin_bit_cast(u64, pk));
      if (MODE == 2) {
#pragma unroll
        for (int jj = 0; jj < 4; ++jj)
          hrow[(r0 + rt * 16 + l4 * 4 + jj) * 68 + wc * 16 + l15] = hn[jj];
      }
    }
    if (MODE == 2) {
      __syncthreads();
      if (tid < 64) {
        float acc = projB[0];
        const float* hr = hrow + tid * 68;
#pragma unroll
        for (int hid = 0; hid < 64; ++hid) acc = fmaf(hr[hid], projW[hid], acc);
        outp[b * 3072 + n0 + tid] = acc;            // host-read output
        astf(xdout + b * 256 + n0 + tid, acc);      // cross-block feedback
      }
    }
  }
}

// ---------------- persistent main kernel (256 blocks x 512) ----------------
__launch_bounds__(512, 2)
__global__ void dcrnn_main(KP p) {
  __shared__ __align__(16) unsigned short xsT[128 * 264];   // 67584 B
  __shared__ __align__(16) unsigned short Hbuf[64 * 136];   // 17408 B -> 84992 total, 1 blk/CU
  const int tid = threadIdx.x;
  const int i = (int)blockIdx.x;
  const int q = (i >> 3) & 3;
  const int b = (i & 7) + 8 * (i >> 5);   // batch's 4 blocks share blockIdx%8 (same XCD)
  const int n0 = q * 64;

  // one-time LDS zero (pads + NaN-pattern protection for first stage)
  for (int e = tid; e < 128 * 264; e += 512) xsT[e] = 0;
  for (int e = tid; e < 64 * 136; e += 512) Hbuf[e] = 0;
  __syncthreads();

  unsigned* ctr = p.ctr + b * 64;
  unsigned st = 0;
  auto BAR = [&]() {
    ++st;
    asm volatile("s_waitcnt vmcnt(0)" ::: "memory");  // state stores visible
    __syncthreads();
    if (tid == 0) {
      __hip_atomic_fetch_add(ctr, 1u, __ATOMIC_RELAXED, __HIP_MEMORY_SCOPE_AGENT);
      const unsigned target = st * 4u;
      while (__hip_atomic_load(ctr, __ATOMIC_RELAXED, __HIP_MEMORY_SCOPE_AGENT) < target)
        __builtin_amdgcn_s_sleep(2);
    }
    __syncthreads();
  };

  f32x4 h0[2], h1[2], u[2];
#pragma unroll
  for (int rt = 0; rt < 2; ++rt) { h0[rt] = 0.f; h1[rt] = 0.f; u[rt] = 0.f; }
  int c0 = 0, c1 = 0;

  // ---- encoder ----
  for (int t = 0; t < 12; ++t) {
    const float* x0 = p.enc_in + (b * 12 + t) * 512;
    dc_stage<2, 96, 0, true >(b, n0, tid, x0, nullptr, p.H0[c0] + b * 16384, p.A, p.Wp[0], p.bias[0],
                              h0, u, p.RH0 + b * 16384, nullptr, nullptr, nullptr, nullptr, xsT, Hbuf);
    BAR();
    dc_stage<2, 96, 1, false>(b, n0, tid, x0, nullptr, p.RH0 + b * 16384, p.A, p.Wp[1], p.bias[1],
                              h0, u, p.H0[c0 ^ 1] + b * 16384, nullptr, nullptr, nullptr, nullptr, xsT, Hbuf);
    BAR(); c0 ^= 1;
    dc_stage<64, 128, 0, true >(b, n0, tid, nullptr, p.H0[c0] + b * 16384, p.H1[c1] + b * 16384, p.A, p.Wp[2], p.bias[2],
                                h1, u, p.RH1 + b * 16384, nullptr, nullptr, nullptr, nullptr, xsT, Hbuf);
    BAR();
    dc_stage<64, 128, 1, false>(b, n0, tid, nullptr, p.H0[c0] + b * 16384, p.RH1 + b * 16384, p.A, p.Wp[3], p.bias[3],
                                h1, u, p.H1[c1 ^ 1] + b * 16384, nullptr, nullptr, nullptr, nullptr, xsT, Hbuf);
    BAR(); c1 ^= 1;
  }

  // ---- decoder ----
  for (int t = 0; t < 12; ++t) {
    const float* xd = t ? (p.XD + b * 256) : nullptr;
    dc_stage<1, 96, 0, true >(b, n0, tid, xd, nullptr, p.H0[c0] + b * 16384, p.A, p.Wp[4], p.bias[4],
                              h0, u, p.RH0 + b * 16384, nullptr, nullptr, nullptr, nullptr, xsT, Hbuf);
    BAR();
    dc_stage<1, 96, 1, false>(b, n0, tid, xd, nullptr, p.RH0 + b * 16384, p.A, p.Wp[5], p.bias[5],
                              h0, u, p.H0[c0 ^ 1] + b * 16384, nullptr, nullptr, nullptr, nullptr, xsT, Hbuf);
    BAR(); c0 ^= 1;
    dc_stage<64, 128, 0, true >(b, n0, tid, nullptr, p.H0[c0] + b * 16384, p.H1[c1] + b * 16384, p.A, p.Wp[6], p.bias[6],
                                h1, u, p.RH1 + b * 16384, nullptr, nullptr, nullptr, nullptr, xsT, Hbuf);
    BAR();
    dc_stage<64, 128, 2, false>(b, n0, tid, nullptr, p.H0[c0] + b * 16384, p.RH1 + b * 16384, p.A, p.Wp[7], p.bias[7],
                                h1, u, p.H1[c1 ^ 1] + b * 16384, p.prW, p.prB, p.out + t * 256, p.XD, xsT, Hbuf);
    if (t != 11) BAR();
    c1 ^= 1;
  }
}

// ---------------- host ----------------
extern "C" void kernel_launch(void* const* d_in, const int* in_sizes, int n_in,
                              void* d_out, int out_size, void* d_ws, size_t ws_size,
                              hipStream_t stream)
{
  (void)in_sizes; (void)n_in; (void)out_size; (void)ws_size;
  KP p;
  p.enc_in = (const float*)d_in[0];
  p.sup0 = (const float*)d_in[2];
  p.sup1 = (const float*)d_in[3];
  p.Wsrc[0] = (const float*)d_in[4];  p.bias[0] = (const float*)d_in[5];
  p.Wsrc[1] = (const float*)d_in[6];  p.bias[1] = (const float*)d_in[7];
  p.Wsrc[2] = (const float*)d_in[8];  p.bias[2] = (const float*)d_in[9];
  p.Wsrc[3] = (const float*)d_in[10]; p.bias[3] = (const float*)d_in[11];
  p.Wsrc[4] = (const float*)d_in[12]; p.bias[4] = (const float*)d_in[13];
  p.Wsrc[5] = (const float*)d_in[14]; p.bias[5] = (const float*)d_in[15];
  p.Wsrc[6] = (const float*)d_in[16]; p.bias[6] = (const float*)d_in[17];
  p.Wsrc[7] = (const float*)d_in[18]; p.bias[7] = (const float*)d_in[19];
  p.prW = (const float*)d_in[20];
  p.prB = (const float*)d_in[21];
  p.out = (float*)d_out;

  char* ws = (char*)d_ws;
  size_t off = 0;
  auto carve = [&](size_t bytes) -> char* {
    char* qp = ws + off;
    off += (bytes + 255) & ~(size_t)255;
    return qp;
  };
  p.A = (unsigned short*)carve(4 * 65536 * 2);
  p.Wp[0] = (unsigned short*)carve(128 * 480 * 2);
  p.Wp[1] = (unsigned short*)carve(64 * 480 * 2);
  p.Wp[2] = (unsigned short*)carve(128 * 640 * 2);
  p.Wp[3] = (unsigned short*)carve(64 * 640 * 2);
  p.Wp[4] = (unsigned short*)carve(128 * 480 * 2);
  p.Wp[5] = (unsigned short*)carve(64 * 480 * 2);
  p.Wp[6] = (unsigned short*)carve(128 * 640 * 2);
  p.Wp[7] = (unsigned short*)carve(64 * 640 * 2);
  p.H0[0] = (unsigned short*)carve(64 * 64 * 256 * 2);
  p.H0[1] = (unsigned short*)carve(64 * 64 * 256 * 2);
  p.H1[0] = (unsigned short*)carve(64 * 64 * 256 * 2);
  p.H1[1] = (unsigned short*)carve(64 * 64 * 256 * 2);
  p.RH0 = (unsigned short*)carve(64 * 64 * 256 * 2);
  p.RH1 = (unsigned short*)carve(64 * 64 * 256 * 2);
  p.XD = (float*)carve(64 * 256 * 4);
  p.ctr = (unsigned*)carve(64 * 256);

  prep<<<dim3(512), dim3(256), 0, stream>>>(p);
  dcrnn_main<<<dim3(256), dim3(512), 0, stream>>>(p);
}